// Round 3
// baseline (286.399 us; speedup 1.0000x reference)
//
#include <hip/hip_runtime.h>

// Problem constants (fixed by setup_inputs in the reference):
//   feature_map: (1, 256, 256, 256) fp32, NHWC
//   rois:        (2000, 5) int32  [batch, x, y, w, h]
//   pool_size:   7
#define FH 256
#define FW 256
#define FC 256
#define POOL 7

// Spatial binning: 16x16-pixel tiles over the 256x256 image -> 256 tiles.
#define TILE_SHIFT 4
#define TILES_X (FW >> TILE_SHIFT)                 // 16
#define NTILES (TILES_X * (FH >> TILE_SHIFT))     // 256

typedef float f32x4 __attribute__((ext_vector_type(4)));

// ---------------------------------------------------------------------------
// Per-cell coordinate math (shared by binning and pooling). Matches the
// reference bilinear-resize half-pixel-center sampling exactly.
// ---------------------------------------------------------------------------
__device__ __forceinline__ int cell_tile(const int* __restrict__ rois, int cell)
{
    int pi  = cell % POOL;
    int tmp = cell / POOL;
    int pj  = tmp % POOL;
    int roi = tmp / POOL;
    int rx = rois[roi * 5 + 1];
    int ry = rois[roi * 5 + 2];
    int rw = rois[roi * 5 + 3];
    int rh = rois[roi * 5 + 4];

    float fy = ((float)pj + 0.5f) * ((float)rh / (float)POOL) - 0.5f;
    fy = fminf(fmaxf(fy, 0.0f), (float)rh - 1.0f);
    int y0 = ry + (int)floorf(fy);

    float fx = ((float)pi + 0.5f) * ((float)rw / (float)POOL) - 0.5f;
    fx = fminf(fmaxf(fx, 0.0f), (float)rw - 1.0f);
    int x0 = rx + (int)floorf(fx);

    return (y0 >> TILE_SHIFT) * TILES_X + (x0 >> TILE_SHIFT);
}

// ---------------------------------------------------------------------------
// Pass 0: zero the global histogram.
// ---------------------------------------------------------------------------
__global__ void zero_kernel(int* __restrict__ hist)
{
    hist[threadIdx.x] = 0;
}

// ---------------------------------------------------------------------------
// Pass 1: per-block LDS histogram of cell->tile, merged into global hist.
// blockDim.x == 256 == NTILES.
// ---------------------------------------------------------------------------
__global__ __launch_bounds__(256) void hist_kernel(
    const int* __restrict__ rois, int* __restrict__ hist, int n_cells)
{
    __shared__ int lh[NTILES];
    int tid = threadIdx.x;
    lh[tid] = 0;
    __syncthreads();
    int c = blockIdx.x * blockDim.x + tid;
    if (c < n_cells) atomicAdd(&lh[cell_tile(rois, c)], 1);
    __syncthreads();
    int v = lh[tid];
    if (v) atomicAdd(&hist[tid], v);
}

// ---------------------------------------------------------------------------
// Pass 2: exclusive prefix sum (256 entries, single block). Serial on one
// lane — 256 adds is trivial next to the 70us pool kernel.
// ---------------------------------------------------------------------------
__global__ void scan_kernel(const int* __restrict__ hist, int* __restrict__ cursor)
{
    __shared__ int tmp[NTILES];
    int i = threadIdx.x;
    tmp[i] = hist[i];
    __syncthreads();
    if (i == 0) {
        int acc = 0;
        for (int k = 0; k < NTILES; ++k) { int v = tmp[k]; tmp[k] = acc; acc += v; }
    }
    __syncthreads();
    cursor[i] = tmp[i];
}

// ---------------------------------------------------------------------------
// Pass 3: scatter cell ids into tile-sorted order. Order within a tile is
// atomics-nondeterministic; each cell appears exactly once, and the pool
// kernel's output is independent of within-tile order.
// ---------------------------------------------------------------------------
__global__ __launch_bounds__(256) void scatter_kernel(
    const int* __restrict__ rois, int* __restrict__ cursor,
    int* __restrict__ sorted, int n_cells)
{
    int c = blockIdx.x * blockDim.x + threadIdx.x;
    if (c >= n_cells) return;
    int t = cell_tile(rois, c);
    int pos = atomicAdd(&cursor[t], 1);
    sorted[pos] = c;
}

// ---------------------------------------------------------------------------
// Pass 4: the pool kernel, one wave (64 lanes) per tile-sorted cell; each
// lane handles 4 channels (float4). Chunked XCD swizzle keeps contiguous
// sorted ranges (= contiguous tiles) on one XCD's L2, so the ~6x cross-ROI
// tap overlap becomes L2 hits instead of HBM re-fetch.
// ---------------------------------------------------------------------------
__global__ __launch_bounds__(256) void roi_pool_kernel(
    const float* __restrict__ fm,
    const int*   __restrict__ rois,
    const int*   __restrict__ sorted,
    float*       __restrict__ out,
    int n_cells)
{
    // Chunked XCD swizzle (bijective for any gridDim; m204 formula).
    int nwg  = gridDim.x;
    int q    = nwg >> 3;
    int rr   = nwg & 7;
    int xcd  = blockIdx.x & 7;
    int slot = blockIdx.x >> 3;
    int base = (xcd < rr) ? xcd * (q + 1) : rr * (q + 1) + (xcd - rr) * q;
    int lb   = base + slot;            // logical block id, contiguous per XCD

    int widx = lb * 4 + ((int)threadIdx.x >> 6);   // wave index = sorted slot
    if (widx >= n_cells) return;
    int lane = threadIdx.x & 63;

    int cell = sorted[widx];
    int pi   = cell % POOL;
    int tmp  = cell / POOL;
    int pj   = tmp % POOL;
    int roi  = tmp / POOL;

    int rx = rois[roi * 5 + 1];
    int ry = rois[roi * 5 + 2];
    int rw = rois[roi * 5 + 3];
    int rh = rois[roi * 5 + 4];

    float lfh = (float)rh;
    float fy  = ((float)pj + 0.5f) * (lfh / (float)POOL) - 0.5f;
    fy = fminf(fmaxf(fy, 0.0f), lfh - 1.0f);
    int   j0 = (int)floorf(fy);
    int   j1 = min(j0 + 1, rh - 1);
    float wy = fy - (float)j0;
    int   y0 = ry + j0;
    int   y1 = ry + j1;

    float lfw = (float)rw;
    float fx  = ((float)pi + 0.5f) * (lfw / (float)POOL) - 0.5f;
    fx = fminf(fmaxf(fx, 0.0f), lfw - 1.0f);
    int   i0 = (int)floorf(fx);
    int   i1 = min(i0 + 1, rw - 1);
    float wx = fx - (float)i0;
    int   x0 = rx + i0;
    int   x1 = rx + i1;

    const f32x4* p00 = (const f32x4*)(fm + ((size_t)y0 * FW + x0) * FC) + lane;
    const f32x4* p01 = (const f32x4*)(fm + ((size_t)y0 * FW + x1) * FC) + lane;
    const f32x4* p10 = (const f32x4*)(fm + ((size_t)y1 * FW + x0) * FC) + lane;
    const f32x4* p11 = (const f32x4*)(fm + ((size_t)y1 * FW + x1) * FC) + lane;

    f32x4 a = *p00;
    f32x4 b = *p01;
    f32x4 c = *p10;
    f32x4 d = *p11;

    float owx = 1.0f - wx;
    float owy = 1.0f - wy;

    f32x4 top = a * owx + b * wx;
    f32x4 bot = c * owx + d * wx;
    f32x4 res = top * owy + bot * wy;

    // Output is write-once, never re-read: evict-first so the 98 MB write
    // stream doesn't displace feature-map lines in L2.
    f32x4* o = (f32x4*)(out + (size_t)cell * FC) + lane;
    __builtin_nontemporal_store(res, o);
}

// ---------------------------------------------------------------------------
// Fallback (workspace too small): direct ROI-order kernel from round 2.
// ---------------------------------------------------------------------------
__global__ __launch_bounds__(256) void roi_pool_direct(
    const float* __restrict__ fm,
    const int*   __restrict__ rois,
    float*       __restrict__ out,
    int n_rois)
{
    int t = blockIdx.x * blockDim.x + (int)threadIdx.x;
    int total = n_rois * POOL * POOL * (FC / 4);
    if (t >= total) return;

    int lane = t & 63;
    int cell = t >> 6;
    int pi   = cell % POOL;
    int tmp  = cell / POOL;
    int pj   = tmp % POOL;
    int roi  = tmp / POOL;

    int rx = rois[roi * 5 + 1];
    int ry = rois[roi * 5 + 2];
    int rw = rois[roi * 5 + 3];
    int rh = rois[roi * 5 + 4];

    float lfh = (float)rh;
    float fy  = ((float)pj + 0.5f) * (lfh / (float)POOL) - 0.5f;
    fy = fminf(fmaxf(fy, 0.0f), lfh - 1.0f);
    int   j0 = (int)floorf(fy);
    int   j1 = min(j0 + 1, rh - 1);
    float wy = fy - (float)j0;
    int   y0 = ry + j0;
    int   y1 = ry + j1;

    float lfw = (float)rw;
    float fx  = ((float)pi + 0.5f) * (lfw / (float)POOL) - 0.5f;
    fx = fminf(fmaxf(fx, 0.0f), lfw - 1.0f);
    int   i0 = (int)floorf(fx);
    int   i1 = min(i0 + 1, rw - 1);
    float wx = fx - (float)i0;
    int   x0 = rx + i0;
    int   x1 = rx + i1;

    const f32x4* p00 = (const f32x4*)(fm + ((size_t)y0 * FW + x0) * FC) + lane;
    const f32x4* p01 = (const f32x4*)(fm + ((size_t)y0 * FW + x1) * FC) + lane;
    const f32x4* p10 = (const f32x4*)(fm + ((size_t)y1 * FW + x0) * FC) + lane;
    const f32x4* p11 = (const f32x4*)(fm + ((size_t)y1 * FW + x1) * FC) + lane;

    f32x4 a = *p00;
    f32x4 b = *p01;
    f32x4 c = *p10;
    f32x4 d = *p11;

    float owx = 1.0f - wx;
    float owy = 1.0f - wy;

    f32x4 top = a * owx + b * wx;
    f32x4 bot = c * owx + d * wx;
    f32x4 res = top * owy + bot * wy;

    f32x4* o = (f32x4*)(out + (size_t)cell * FC) + lane;
    __builtin_nontemporal_store(res, o);
}

extern "C" void kernel_launch(void* const* d_in, const int* in_sizes, int n_in,
                              void* d_out, int out_size, void* d_ws, size_t ws_size,
                              hipStream_t stream) {
    const float* fm   = (const float*)d_in[0];
    const int*   rois = (const int*)d_in[1];
    // d_in[2] is pool_size (==7), fixed by the problem; hardcoded as POOL.
    float* out = (float*)d_out;

    int n_rois  = in_sizes[1] / 5;
    int n_cells = n_rois * POOL * POOL;

    size_t ws_need = (size_t)(NTILES * 2 + n_cells) * sizeof(int);
    if (ws_size < ws_need || d_ws == nullptr) {
        // Workspace too small: direct (unsorted) path.
        int total = n_cells * (FC / 4);
        int block = 256;
        int grid  = (total + block - 1) / block;
        roi_pool_direct<<<grid, block, 0, stream>>>(fm, rois, out, n_rois);
        return;
    }

    int* hist   = (int*)d_ws;          // NTILES
    int* cursor = hist + NTILES;       // NTILES
    int* sorted = cursor + NTILES;     // n_cells

    int bin_blocks = (n_cells + 255) / 256;

    zero_kernel<<<1, NTILES, 0, stream>>>(hist);
    hist_kernel<<<bin_blocks, 256, 0, stream>>>(rois, hist, n_cells);
    scan_kernel<<<1, NTILES, 0, stream>>>(hist, cursor);
    scatter_kernel<<<bin_blocks, 256, 0, stream>>>(rois, cursor, sorted, n_cells);

    int pool_blocks = (n_cells + 3) / 4;   // 4 waves (cells) per 256-thread block
    roi_pool_kernel<<<pool_blocks, 256, 0, stream>>>(fm, rois, sorted, out, n_cells);
}

// Round 6
// 184.301 us; speedup vs baseline: 1.5540x; 1.5540x over previous
//
#include <hip/hip_runtime.h>

// Problem constants (fixed by setup_inputs in the reference):
//   feature_map: (1, 256, 256, 256) fp32, NHWC
//   rois:        (2000, 5) int32  [batch, x, y, w, h]
//   pool_size:   7
#define FH 256
#define FW 256
#define FC 256
#define POOL 7

// 16x16-px image tiles. A cell's 4 bilinear taps are a 2x2 adjacent-pixel
// block anchored at (y0,x0), so binning cells by the tile of (y0,x0) gives a
// 17x17-px (289 KB) working set per tile: near-perfect L2 locality.
#define TILE_SHIFT 4
#define TILES_X (FW >> TILE_SHIFT)            // 16
#define TILES_Y (FH >> TILE_SHIFT)            // 16
#define NTILES (TILES_X * TILES_Y)            // 256

// Work decomposition: grid = NTILES * SUBS blocks; block (tile, sub) owns
// cells whose (y0,x0) tap lies in `tile` AND whose roi % SUBS == sub.
// SUBS=32 -> ~8 distinct tiles in flight per XCD (256 resident blocks / 32)
// ~= 2.3 MB < 4 MiB L2, while keeping per-tile load spread over 32 blocks.
#define SUBS 32
#define RBATCH 64                             // ROIs scanned per batch
#define QCAP (RBATCH * POOL * POOL)           // worst case: every cell hits

typedef float f32x4 __attribute__((ext_vector_type(4)));

// Single stateless kernel: no workspace, no global atomics, idempotent —
// safe under any graph-replay/concurrency regime (round-5 failure was a
// stateful multi-kernel sort pipeline diverging only across timed replays).
__global__ __launch_bounds__(256) void roi_pool_tiled(
    const float* __restrict__ fm,
    const int*   __restrict__ rois,
    float*       __restrict__ out,
    int n_rois)
{
    __shared__ int q[QCAP];
    __shared__ int qn;

    // Chunked XCD swizzle (bijective; grid = 8192 is divisible by 8, so this
    // is the plain contiguous-chunk remap). Consecutive logical blocks =
    // same tile's stripes, then the next tile: each XCD owns 32 contiguous
    // tiles (two 16-tile rows = a 32-px image band).
    int nwg  = gridDim.x;
    int qd   = nwg >> 3;
    int rr   = nwg & 7;
    int xcd  = blockIdx.x & 7;
    int slot = blockIdx.x >> 3;
    int base = (xcd < rr) ? xcd * (qd + 1) : rr * (qd + 1) + (xcd - rr) * qd;
    int lb   = base + slot;

    int tile = lb / SUBS;
    int sub  = lb % SUBS;
    int tly  = tile / TILES_X;     // tile-row (y)
    int tlx  = tile % TILES_X;     // tile-col (x)

    int tid  = threadIdx.x;
    int lane = tid & 63;
    int wav  = tid >> 6;

    // ROIs of this stripe: sub, sub+SUBS, sub+2*SUBS, ...
    int nmine = (n_rois > sub) ? (n_rois - sub + SUBS - 1) / SUBS : 0;
    int nbatch = (nmine + RBATCH - 1) / RBATCH;

    for (int b = 0; b < nbatch; ++b) {
        if (tid == 0) qn = 0;
        __syncthreads();

        // ---- scan phase: threads 0..RBATCH-1 each test one ROI ----------
        int j = b * RBATCH + tid;
        if (tid < RBATCH && j < nmine) {
            int roi = sub + j * SUBS;
            int rx = rois[roi * 5 + 1];
            int ry = rois[roi * 5 + 2];
            int rw = rois[roi * 5 + 3];
            int rh = rois[roi * 5 + 4];

            // Which pj rows / pi cols have their (y0,x0) tap in this tile?
            // Single code site in a single kernel => identical codegen for
            // all blocks => each cell claimed by exactly one block.
            int ybits = 0, xbits = 0;
            for (int p = 0; p < POOL; ++p) {
                float fy = ((float)p + 0.5f) * ((float)rh / (float)POOL) - 0.5f;
                fy = fminf(fmaxf(fy, 0.0f), (float)rh - 1.0f);
                int y0 = ry + (int)floorf(fy);
                if ((y0 >> TILE_SHIFT) == tly) ybits |= 1 << p;

                float fx = ((float)p + 0.5f) * ((float)rw / (float)POOL) - 0.5f;
                fx = fminf(fmaxf(fx, 0.0f), (float)rw - 1.0f);
                int x0 = rx + (int)floorf(fx);
                if ((x0 >> TILE_SHIFT) == tlx) xbits |= 1 << p;
            }
            if (ybits && xbits) {
                int cnt = __popc(ybits) * __popc(xbits);
                int p0  = atomicAdd(&qn, cnt);          // LDS atomic: fast
                for (int pj = 0; pj < POOL; ++pj) if (ybits & (1 << pj))
                    for (int pi = 0; pi < POOL; ++pi) if (xbits & (1 << pi))
                        q[p0++] = (roi * POOL + pj) * POOL + pi;
            }
        }
        __syncthreads();

        // ---- drain phase: one wave per queued cell, 64 lanes x float4 ----
        int n = qn;
        for (int i = wav; i < n; i += 4) {
            int cell = q[i];                  // LDS broadcast, wave-uniform
            int pi   = cell % POOL;
            int tmp  = cell / POOL;
            int pj   = tmp % POOL;
            int roi  = tmp / POOL;

            int rx = rois[roi * 5 + 1];
            int ry = rois[roi * 5 + 2];
            int rw = rois[roi * 5 + 3];
            int rh = rois[roi * 5 + 4];

            float lfh = (float)rh;
            float fy  = ((float)pj + 0.5f) * (lfh / (float)POOL) - 0.5f;
            fy = fminf(fmaxf(fy, 0.0f), lfh - 1.0f);
            int   j0 = (int)floorf(fy);
            int   j1 = min(j0 + 1, rh - 1);
            float wy = fy - (float)j0;
            int   y0 = ry + j0;
            int   y1 = ry + j1;

            float lfw = (float)rw;
            float fx  = ((float)pi + 0.5f) * (lfw / (float)POOL) - 0.5f;
            fx = fminf(fmaxf(fx, 0.0f), lfw - 1.0f);
            int   i0 = (int)floorf(fx);
            int   i1 = min(i0 + 1, rw - 1);
            float wx = fx - (float)i0;
            int   x0 = rx + i0;
            int   x1 = rx + i1;

            const f32x4* p00 = (const f32x4*)(fm + ((size_t)y0 * FW + x0) * FC) + lane;
            const f32x4* p01 = (const f32x4*)(fm + ((size_t)y0 * FW + x1) * FC) + lane;
            const f32x4* p10 = (const f32x4*)(fm + ((size_t)y1 * FW + x0) * FC) + lane;
            const f32x4* p11 = (const f32x4*)(fm + ((size_t)y1 * FW + x1) * FC) + lane;

            f32x4 a = *p00;
            f32x4 bb = *p01;
            f32x4 c = *p10;
            f32x4 d = *p11;

            float owx = 1.0f - wx;
            float owy = 1.0f - wy;

            f32x4 top = a * owx + bb * wx;
            f32x4 bot = c * owx + d * wx;
            f32x4 res = top * owy + bot * wy;

            // Write-once output: evict-first so the 98 MB write stream
            // doesn't displace feature-map lines in L2.
            f32x4* o = (f32x4*)(out + (size_t)cell * FC) + lane;
            __builtin_nontemporal_store(res, o);
        }
        __syncthreads();   // protect qn reset of next batch vs this drain
    }
}

extern "C" void kernel_launch(void* const* d_in, const int* in_sizes, int n_in,
                              void* d_out, int out_size, void* d_ws, size_t ws_size,
                              hipStream_t stream) {
    const float* fm   = (const float*)d_in[0];
    const int*   rois = (const int*)d_in[1];
    // d_in[2] is pool_size (==7), fixed by the problem; hardcoded as POOL.
    float* out = (float*)d_out;

    int n_rois = in_sizes[1] / 5;

    int grid = NTILES * SUBS;   // 8192 blocks, independent of data
    roi_pool_tiled<<<grid, 256, 0, stream>>>(fm, rois, out, n_rois);
}

// Round 8
// 183.268 us; speedup vs baseline: 1.5627x; 1.0056x over previous
//
#include <hip/hip_runtime.h>

// Problem constants (fixed by setup_inputs in the reference):
//   feature_map: (1, 256, 256, 256) fp32, NHWC
//   rois:        (2000, 5) int32  [batch, x, y, w, h]
//   pool_size:   7
#define FH 256
#define FW 256
#define FC 256
#define POOL 7
#define CPW 4   // cells per wave (98000 % 4 == 0 -> no slot guards needed)

typedef float f32x4 __attribute__((ext_vector_type(4)));

// Round-7 theory: kernel is memory-LATENCY-bound, not bytes-bound (round 6
// cut HBM fetch 170->28 MB with zero time change; VALUBusy only ~27%).
// Fix: 4 cells per wave, all 16 tap loads issued back-to-back before any
// use -> 4x memory-level parallelism per wave, 4 KB contiguous stores.
// Static unrolling via macros: every register is compile-time named (no
// runtime-indexed arrays -> no scratch).

#define COORD(k) \
    int   cell##k = min(base + k, n_cells - 1); \
    int   pi##k  = cell##k % POOL; \
    int   tq##k  = cell##k / POOL; \
    int   pj##k  = tq##k % POOL; \
    int   roi##k = tq##k / POOL; \
    int   rx##k  = rois[roi##k * 5 + 1]; \
    int   ry##k  = rois[roi##k * 5 + 2]; \
    int   rw##k  = rois[roi##k * 5 + 3]; \
    int   rh##k  = rois[roi##k * 5 + 4]; \
    float fy##k  = fminf(fmaxf(((float)pj##k + 0.5f) * ((float)rh##k / (float)POOL) - 0.5f, 0.0f), (float)rh##k - 1.0f); \
    int   j0##k  = (int)floorf(fy##k); \
    int   j1##k  = min(j0##k + 1, rh##k - 1); \
    float wy##k  = fy##k - (float)j0##k; \
    float fx##k  = fminf(fmaxf(((float)pi##k + 0.5f) * ((float)rw##k / (float)POOL) - 0.5f, 0.0f), (float)rw##k - 1.0f); \
    int   i0##k  = (int)floorf(fx##k); \
    int   i1##k  = min(i0##k + 1, rw##k - 1); \
    float wx##k  = fx##k - (float)i0##k; \
    const f32x4* p00##k = (const f32x4*)(fm + ((size_t)(ry##k + j0##k) * FW + (rx##k + i0##k)) * FC) + lane; \
    const f32x4* p01##k = (const f32x4*)(fm + ((size_t)(ry##k + j0##k) * FW + (rx##k + i1##k)) * FC) + lane; \
    const f32x4* p10##k = (const f32x4*)(fm + ((size_t)(ry##k + j1##k) * FW + (rx##k + i0##k)) * FC) + lane; \
    const f32x4* p11##k = (const f32x4*)(fm + ((size_t)(ry##k + j1##k) * FW + (rx##k + i1##k)) * FC) + lane;

#define LOADS(k) \
    f32x4 a##k = *p00##k; \
    f32x4 b##k = *p01##k; \
    f32x4 c##k = *p10##k; \
    f32x4 d##k = *p11##k;

#define FINISH(k) \
    { \
        float owx = 1.0f - wx##k; \
        float owy = 1.0f - wy##k; \
        f32x4 top = a##k * owx + b##k * wx##k; \
        f32x4 bot = c##k * owx + d##k * wx##k; \
        f32x4 res = top * owy + bot * wy##k; \
        __builtin_nontemporal_store(res, (f32x4*)(out + (size_t)cell##k * FC) + lane); \
    }

__global__ __launch_bounds__(256) void roi_pool_mlp(
    const float* __restrict__ fm,
    const int*   __restrict__ rois,
    float*       __restrict__ out,
    int n_cells)
{
    // Chunked XCD swizzle (bijective for any gridDim; m204 formula) — kept
    // from the round-2 baseline so batching is the only changed variable.
    int nwg  = gridDim.x;
    int q    = nwg >> 3;
    int rr   = nwg & 7;
    int xcd  = blockIdx.x & 7;
    int slot = blockIdx.x >> 3;
    int bse  = (xcd < rr) ? xcd * (q + 1) : rr * (q + 1) + (xcd - rr) * q;
    int lb   = bse + slot;

    int wid  = lb * 4 + ((int)threadIdx.x >> 6);   // global wave id
    int lane = threadIdx.x & 63;                   // float4 channel group

    int base = wid * CPW;                          // first cell of this wave
    if (base >= n_cells) return;

    // Coordinate + address math for all 4 cells (VALU, no memory waits).
    COORD(0) COORD(1) COORD(2) COORD(3)

    // All 16 independent 1 KB tap loads in flight at once.
    LOADS(0) LOADS(1) LOADS(2) LOADS(3)

    // Bilinear blends + 4 contiguous 1 KB stores (4 KB span per wave).
    FINISH(0) FINISH(1) FINISH(2) FINISH(3)
}

extern "C" void kernel_launch(void* const* d_in, const int* in_sizes, int n_in,
                              void* d_out, int out_size, void* d_ws, size_t ws_size,
                              hipStream_t stream) {
    const float* fm   = (const float*)d_in[0];
    const int*   rois = (const int*)d_in[1];
    // d_in[2] is pool_size (==7), fixed by the problem; hardcoded as POOL.
    float* out = (float*)d_out;

    int n_rois  = in_sizes[1] / 5;
    int n_cells = n_rois * POOL * POOL;

    int waves = (n_cells + CPW - 1) / CPW;         // one wave per 4 cells
    int grid  = (waves + 3) / 4;                   // 4 waves per 256-thr block

    roi_pool_mlp<<<grid, 256, 0, stream>>>(fm, rois, out, n_cells);
}